// Round 3
// baseline (1159.472 us; speedup 1.0000x reference)
//
#include <hip/hip_runtime.h>
#include <math.h>

#pragma clang fp contract(off)

#define RR 7
#define HH 2048
#define WW 2048
#define PH 2062
#define PW 2062
#define PITCH 2080
#define PLANE (PITCH * PH)

#define BLK 256
#define WOUT 496        // output cols per block (threads 0..247, 2 cols each)
#define TYB 16          // output rows per block (multiple of 16)
#define GX 5            // 5*496 = 2480 >= 2062
#define GY 129          // 129*16 = 2064 >= 2062

__global__ __launch_bounds__(256) void sw_pad(const float* __restrict__ img,
                                              float* __restrict__ dst) {
    int idx = blockIdx.x * blockDim.x + threadIdx.x;
    if (idx >= PW * PH) return;
    int y = idx / PW, x = idx - y * PW;
    int sy = y - RR; sy = sy < 0 ? 0 : (sy > HH - 1 ? HH - 1 : sy);
    int sx = x - RR; sx = sx < 0 ? 0 : (sx > WW - 1 ? WW - 1 : sx);
    const float* p = img + ((long)sy * WW + sx) * 3;
    long o = (long)y * PITCH + x;
    dst[o] = p[0];
    dst[(long)PLANE + o] = p[1];
    dst[2L * PLANE + o] = p[2];
}

__global__ __launch_bounds__(256) void sw_crop(const float* __restrict__ src,
                                               float* __restrict__ out) {
    int idx = blockIdx.x * blockDim.x + threadIdx.x;
    if (idx >= HH * WW) return;
    int y = idx / WW, x = idx - y * WW;
    long o = (long)(y + RR) * PITCH + (x + RR);
    out[(long)idx * 3 + 0] = src[o];
    out[(long)idx * 3 + 1] = src[(long)PLANE + o];
    out[(long)idx * 3 + 2] = src[2L * PLANE + o];
}

// Streaming tap update for one pixel. i = tap index 0..14 (compile-time).
// Chains identical to the verified baseline: hL8 = taps 0..7, hR8 = taps 7..14,
// hF15 = taps 0..14, sequential ascending, mul-then-add, contract off.
// (Round-2 lesson: do NOT re-round these chains — the argmin selector flips on
// ulp-level changes and the 10-iter recurrence amplifies past tolerance.)
#define PX_TAP(q, i, aLx, aLy, aLz, aRx, aRy, aRz, fx, fy, xc)                          \
    do {                                                                                \
        if ((i) == 0) {                                                                 \
            aLx = 0.125f * (q).x; aLy = 0.125f * (q).y; aLz = 0.125f * (q).z;           \
            fx = c15 * (q).x; fy = c15 * (q).y;                                         \
        } else {                                                                        \
            if ((i) <= 7) {                                                             \
                aLx = aLx + 0.125f * (q).x; aLy = aLy + 0.125f * (q).y;                 \
                aLz = aLz + 0.125f * (q).z;                                             \
            }                                                                           \
            if ((i) == 7) {                                                             \
                aRx = 0.125f * (q).x; aRy = 0.125f * (q).y; aRz = 0.125f * (q).z;       \
                xc = (q).w;                                                             \
            }                                                                           \
            if ((i) > 7 && (i) <= 14) {                                                 \
                aRx = aRx + 0.125f * (q).x; aRy = aRy + 0.125f * (q).y;                 \
                aRz = aRz + 0.125f * (q).z;                                             \
            }                                                                           \
            if ((i) <= 14) { fx = fx + c15 * (q).x; fy = fy + c15 * (q).y; }            \
        }                                                                               \
    } while (0)

__global__ __launch_bounds__(BLK) void sw_iter(const float* __restrict__ src,
                                               float* __restrict__ dst) {
    // [chunk-row 0..3][half 0..1][col-idx 0..255], float4 {o1L,o1R,o1F,x}: 32 KB
    // even/odd phase split -> horizontal taps are 16 B/lane stride (conflict-free)
    __shared__ float4 lds4[4 * 512];
    const int tid = threadIdx.x;
    const int x0 = blockIdx.x * WOUT;
    const int y0 = blockIdx.y * TYB;          // multiple of 16
    const int z = blockIdx.z;
    const float* sp = src + (long)z * PLANE;
    float* dp = dst + (long)z * PLANE;

    const int gc0 = x0 - 8 + 2 * tid;         // this thread's even staged col
    const bool gok = (gc0 >= 0) && (gc0 < PW);   // gc0 even, PW even -> pair mask
    const int oc0 = x0 + 2 * tid;             // this thread's even output col
    const bool comp = (tid < WOUT / 2) && (oc0 < PW);

    const float c15 = 1.0f / 15.0f;

    // register rings: input rows (slot = row & 15) for the 2 staged cols
    float xa[16], xb[16];
#pragma unroll
    for (int i = 0; i < 16; ++i) { xa[i] = 0.0f; xb[i] = 0.0f; }

    // warm-up: load rows y0-7 .. y0+6 (no vertical compute)
#pragma unroll
    for (int k = 0; k < 14; ++k) {
        const int r = y0 - 7 + k;
        float2 v = make_float2(0.0f, 0.0f);
        if (gok && r >= 0) v = *(const float2*)(sp + (long)r * PITCH + gc0);
        xa[(k + 9) & 15] = v.x;
        xb[(k + 9) & 15] = v.y;
    }

    for (int cc = 0; cc < TYB / 16; ++cc) {
        const int jb16 = 16 * cc;
#pragma unroll
        for (int c4 = 0; c4 < 4; ++c4) {
            __syncthreads();   // previous horizontal pass done with LDS rows
            // ---- vertical stage: o1 rows m = y0+jb16+4*c4+s ----
#pragma unroll
            for (int s = 0; s < 4; ++s) {
                const int jm = 4 * c4 + s;            // row offset mod 16
                const int t = y0 + jb16 + jm + 7;     // newest input row
                float2 v = make_float2(0.0f, 0.0f);
                if (gok && t < PH) v = *(const float2*)(sp + (long)t * PITCH + gc0);
                xa[(jm + 7) & 15] = v.x;
                xb[(jm + 7) & 15] = v.y;

                // vertical chains, taps k = rows m-7+k, slot (jm+9+k)&15
                float aL0 = 0.125f * xa[(jm + 9) & 15];
                float aL1 = 0.125f * xb[(jm + 9) & 15];
#pragma unroll
                for (int k = 1; k < 8; ++k) {
                    aL0 = aL0 + 0.125f * xa[(jm + 9 + k) & 15];
                    aL1 = aL1 + 0.125f * xb[(jm + 9 + k) & 15];
                }
                float aR0 = 0.125f * xa[jm & 15];     // tap k=7 = row m
                float aR1 = 0.125f * xb[jm & 15];
#pragma unroll
                for (int k = 8; k < 15; ++k) {
                    aR0 = aR0 + 0.125f * xa[(jm + 9 + k) & 15];
                    aR1 = aR1 + 0.125f * xb[(jm + 9 + k) & 15];
                }
                float aF0 = c15 * xa[(jm + 9) & 15];
                float aF1 = c15 * xb[(jm + 9) & 15];
#pragma unroll
                for (int k = 1; k < 15; ++k) {
                    aF0 = aF0 + c15 * xa[(jm + 9 + k) & 15];
                    aF1 = aF1 + c15 * xb[(jm + 9 + k) & 15];
                }
                const float X0 = xa[jm & 15];
                const float X1 = xb[jm & 15];
                lds4[s * 512 + tid]       = make_float4(aL0, aR0, aF0, X0); // even col
                lds4[s * 512 + 256 + tid] = make_float4(aL1, aR1, aF1, X1); // odd col
            }
            __syncthreads();
            // ---- horizontal stage ----
            if (comp) {
#pragma unroll 1
                for (int s = 0; s < 4; ++s) {
                    const int m = y0 + jb16 + 4 * c4 + s;
                    if (m >= PH) break;
                    const float4* rowb = lds4 + s * 512;
                    const float4* Eb = rowb + tid + 1;        // even cols 2t+2+2k
                    const float4* Ob = rowb + 256 + tid;      // odd cols 2t+1+2k

                    float a0Lx, a0Ly, a0Lz, a0Rx, a0Ry, a0Rz, f0x, f0y, xc0;
                    float a1Lx, a1Ly, a1Lz, a1Rx, a1Ry, a1Rz, f1x, f1y, xc1;
                    // stream 16 taps: seq[j] = cols oc0-7 .. oc0+8 ascending
#pragma unroll
                    for (int j = 0; j < 16; ++j) {
                        float4 q = (j & 1) ? Eb[(j - 1) >> 1] : Ob[j >> 1];
                        if (j <= 14) PX_TAP(q, j, a0Lx, a0Ly, a0Lz, a0Rx, a0Ry, a0Rz, f0x, f0y, xc0);
                        if (j >= 1)  PX_TAP(q, (j - 1), a1Lx, a1Ly, a1Lz, a1Rx, a1Ry, a1Rz, f1x, f1y, xc1);
                    }

                    float d0 = a0Lx - xc0, d1 = a0Rx - xc0;
                    float d2 = a0Ly - xc0, d3 = a0Ry - xc0;
                    float d4 = f0x - xc0,  d5 = f0y - xc0;
                    float d6 = a0Lz - xc0, d7 = a0Rz - xc0;
                    float best = d0, ba = fabsf(d0), a;
                    a = fabsf(d1); if (a < ba) { ba = a; best = d1; }
                    a = fabsf(d2); if (a < ba) { ba = a; best = d2; }
                    a = fabsf(d3); if (a < ba) { ba = a; best = d3; }
                    a = fabsf(d4); if (a < ba) { ba = a; best = d4; }
                    a = fabsf(d5); if (a < ba) { ba = a; best = d5; }
                    a = fabsf(d6); if (a < ba) { ba = a; best = d6; }
                    a = fabsf(d7); if (a < ba) { ba = a; best = d7; }
                    float out0 = xc0 + best;

                    d0 = a1Lx - xc1; d1 = a1Rx - xc1;
                    d2 = a1Ly - xc1; d3 = a1Ry - xc1;
                    d4 = f1x - xc1;  d5 = f1y - xc1;
                    d6 = a1Lz - xc1; d7 = a1Rz - xc1;
                    best = d0; ba = fabsf(d0);
                    a = fabsf(d1); if (a < ba) { ba = a; best = d1; }
                    a = fabsf(d2); if (a < ba) { ba = a; best = d2; }
                    a = fabsf(d3); if (a < ba) { ba = a; best = d3; }
                    a = fabsf(d4); if (a < ba) { ba = a; best = d4; }
                    a = fabsf(d5); if (a < ba) { ba = a; best = d5; }
                    a = fabsf(d6); if (a < ba) { ba = a; best = d6; }
                    a = fabsf(d7); if (a < ba) { ba = a; best = d7; }
                    float out1 = xc1 + best;

                    *(float2*)(dp + (long)m * PITCH + oc0) = make_float2(out0, out1);
                }
            }
        }
    }
}

extern "C" void kernel_launch(void* const* d_in, const int* in_sizes, int n_in,
                              void* d_out, int out_size, void* d_ws, size_t ws_size,
                              hipStream_t stream) {
    (void)in_sizes; (void)n_in; (void)out_size; (void)ws_size;
    const float* img = (const float*)d_in[0];
    float* out = (float*)d_out;
    float* A = (float*)d_ws;
    float* B = A + 3L * PLANE;

    {
        int total = PW * PH;
        int g = (total + 255) / 256;
        sw_pad<<<dim3(g), dim3(256), 0, stream>>>(img, A);
    }
    dim3 grid(GX, GY, 3), block(BLK);
    for (int i = 0; i < 10; ++i) {
        const float* s = (i & 1) ? B : A;
        float* d = (i & 1) ? A : B;
        sw_iter<<<grid, block, 0, stream>>>(s, d);
    }
    // iter 9 (odd) writes A: final state in A.
    {
        int total = HH * WW;
        int g = (total + 255) / 256;
        sw_crop<<<dim3(g), dim3(256), 0, stream>>>(A, out);
    }
}

// Round 4
// 916.760 us; speedup vs baseline: 1.2647x; 1.2647x over previous
//
#include <hip/hip_runtime.h>
#include <math.h>

#pragma clang fp contract(off)

typedef float v2f __attribute__((ext_vector_type(2)));

#define RR 7
#define HH 2048
#define WW 2048
#define PH 2062
#define PW 2062
#define PITCH 2080
#define PLANE (PITCH * PH)

#define BLK 256
#define WOUT 496        // output cols per block (threads 0..247, 2 cols each)
#define TYB 32          // output rows per block (multiple of 16) -- R3: 16 regressed, keep 32
#define GX 5            // 5*496 = 2480 >= 2062
#define GY 65           // 65*32 = 2080 >= 2062

__global__ __launch_bounds__(256) void sw_pad(const float* __restrict__ img,
                                              float* __restrict__ dst) {
    int idx = blockIdx.x * blockDim.x + threadIdx.x;
    if (idx >= PW * PH) return;
    int y = idx / PW, x = idx - y * PW;
    int sy = y - RR; sy = sy < 0 ? 0 : (sy > HH - 1 ? HH - 1 : sy);
    int sx = x - RR; sx = sx < 0 ? 0 : (sx > WW - 1 ? WW - 1 : sx);
    const float* p = img + ((long)sy * WW + sx) * 3;
    long o = (long)y * PITCH + x;
    dst[o] = p[0];
    dst[(long)PLANE + o] = p[1];
    dst[2L * PLANE + o] = p[2];
}

__global__ __launch_bounds__(256) void sw_crop(const float* __restrict__ src,
                                               float* __restrict__ out) {
    int idx = blockIdx.x * blockDim.x + threadIdx.x;
    if (idx >= HH * WW) return;
    int y = idx / WW, x = idx - y * WW;
    long o = (long)(y + RR) * PITCH + (x + RR);
    out[(long)idx * 3 + 0] = src[o];
    out[(long)idx * 3 + 1] = src[(long)PLANE + o];
    out[(long)idx * 3 + 2] = src[2L * PLANE + o];
}

// Streaming tap update for one pixel, packed channels. i = tap index 0..14.
// hL/hR/hF chains: identical tap order and mul-then-add as verified baseline.
// aL/aR/f are v2f packing the (x,y) channels -- elementwise ops keep each
// component's sequence bit-identical to the scalar version (pk ops are IEEE-
// identical per lane-half; contract off so no fma forms).
#define PX_TAP(q, qxy, i, aL, aLz, aR, aRz, f, xc)                                      \
    do {                                                                                \
        if ((i) == 0) {                                                                 \
            aL = 0.125f * (qxy); aLz = 0.125f * (q).z;                                  \
            f = c15 * (qxy);                                                            \
        } else {                                                                        \
            if ((i) <= 7) {                                                             \
                aL = aL + 0.125f * (qxy); aLz = aLz + 0.125f * (q).z;                   \
            }                                                                           \
            if ((i) == 7) {                                                             \
                aR = 0.125f * (qxy); aRz = 0.125f * (q).z;                              \
                xc = (q).w;                                                             \
            }                                                                           \
            if ((i) > 7 && (i) <= 14) {                                                 \
                aR = aR + 0.125f * (qxy); aRz = aRz + 0.125f * (q).z;                   \
            }                                                                           \
            if ((i) <= 14) { f = f + c15 * (qxy); }                                     \
        }                                                                               \
    } while (0)

__global__ __launch_bounds__(BLK) void sw_iter(const float* __restrict__ src,
                                               float* __restrict__ dst) {
    // [chunk-row 0..3][half 0..1][col-idx 0..255], float4 {o1L,o1R,o1F,x}: 32 KB
    // even/odd phase split -> horizontal taps are 16 B/lane stride (conflict-free)
    __shared__ float4 lds4[4 * 512];
    const int tid = threadIdx.x;
    const int x0 = blockIdx.x * WOUT;
    const int y0 = blockIdx.y * TYB;          // multiple of 16
    const int z = blockIdx.z;
    const float* sp = src + (long)z * PLANE;
    float* dp = dst + (long)z * PLANE;

    const int gc0 = x0 - 8 + 2 * tid;         // this thread's even staged col
    const bool gok = (gc0 >= 0) && (gc0 < PW);   // gc0 even, PW even -> pair mask
    const int oc0 = x0 + 2 * tid;             // this thread's even output col
    const bool comp = (tid < WOUT / 2) && (oc0 < PW);

    const float c15 = 1.0f / 15.0f;

    // register ring: input rows (slot = row & 15), packed {even col, odd col}
    v2f xab[16];
#pragma unroll
    for (int i = 0; i < 16; ++i) { xab[i] = (v2f){0.0f, 0.0f}; }

    // warm-up: load rows y0-7 .. y0+6 (no vertical compute)
#pragma unroll
    for (int k = 0; k < 14; ++k) {
        const int r = y0 - 7 + k;
        v2f v = (v2f){0.0f, 0.0f};
        if (gok && r >= 0) v = *(const v2f*)(sp + (long)r * PITCH + gc0);
        xab[(k + 9) & 15] = v;
    }

    for (int cc = 0; cc < TYB / 16; ++cc) {
        const int jb16 = 16 * cc;
#pragma unroll
        for (int c4 = 0; c4 < 4; ++c4) {
            __syncthreads();   // previous horizontal pass done with LDS rows
            // ---- vertical stage: o1 rows m = y0+jb16+4*c4+s ----
#pragma unroll
            for (int s = 0; s < 4; ++s) {
                const int jm = 4 * c4 + s;            // row offset mod 16
                const int t = y0 + jb16 + jm + 7;     // newest input row
                v2f v = (v2f){0.0f, 0.0f};
                if (gok && t < PH) v = *(const v2f*)(sp + (long)t * PITCH + gc0);
                xab[(jm + 7) & 15] = v;

                // vertical chains, taps k = rows m-7+k, slot (jm+9+k)&15
                // packed even/odd columns; per-component order identical to baseline
                v2f aL = 0.125f * xab[(jm + 9) & 15];
#pragma unroll
                for (int k = 1; k < 8; ++k) {
                    aL = aL + 0.125f * xab[(jm + 9 + k) & 15];
                }
                v2f aR = 0.125f * xab[jm & 15];       // tap k=7 = row m
#pragma unroll
                for (int k = 8; k < 15; ++k) {
                    aR = aR + 0.125f * xab[(jm + 9 + k) & 15];
                }
                v2f aF = c15 * xab[(jm + 9) & 15];
#pragma unroll
                for (int k = 1; k < 15; ++k) {
                    aF = aF + c15 * xab[(jm + 9 + k) & 15];
                }
                const v2f X = xab[jm & 15];
                lds4[s * 512 + tid]       = make_float4(aL.x, aR.x, aF.x, X.x); // even col
                lds4[s * 512 + 256 + tid] = make_float4(aL.y, aR.y, aF.y, X.y); // odd col
            }
            __syncthreads();
            // ---- horizontal stage ----
            if (comp) {
#pragma unroll 1
                for (int s = 0; s < 4; ++s) {
                    const int m = y0 + jb16 + 4 * c4 + s;
                    if (m >= PH) break;
                    const float4* rowb = lds4 + s * 512;
                    const float4* Eb = rowb + tid + 1;        // even cols 2t+2+2k
                    const float4* Ob = rowb + 256 + tid;      // odd cols 2t+1+2k

                    v2f a0L, a0R, f0; float a0Lz, a0Rz, xc0;
                    v2f a1L, a1R, f1; float a1Lz, a1Rz, xc1;
                    // stream 16 taps: seq[j] = cols oc0-7 .. oc0+8 ascending
#pragma unroll
                    for (int j = 0; j < 16; ++j) {
                        float4 q = (j & 1) ? Eb[(j - 1) >> 1] : Ob[j >> 1];
                        v2f qxy = (v2f){q.x, q.y};
                        if (j <= 14) PX_TAP(q, qxy, j, a0L, a0Lz, a0R, a0Rz, f0, xc0);
                        if (j >= 1)  PX_TAP(q, qxy, (j - 1), a1L, a1Lz, a1R, a1Rz, f1, xc1);
                    }

                    // argmin: scalar, candidate order identical to baseline
                    float d0 = a0L.x - xc0, d1 = a0R.x - xc0;
                    float d2 = a0L.y - xc0, d3 = a0R.y - xc0;
                    float d4 = f0.x - xc0,  d5 = f0.y - xc0;
                    float d6 = a0Lz - xc0,  d7 = a0Rz - xc0;
                    float best = d0, ba = fabsf(d0), a;
                    a = fabsf(d1); if (a < ba) { ba = a; best = d1; }
                    a = fabsf(d2); if (a < ba) { ba = a; best = d2; }
                    a = fabsf(d3); if (a < ba) { ba = a; best = d3; }
                    a = fabsf(d4); if (a < ba) { ba = a; best = d4; }
                    a = fabsf(d5); if (a < ba) { ba = a; best = d5; }
                    a = fabsf(d6); if (a < ba) { ba = a; best = d6; }
                    a = fabsf(d7); if (a < ba) { ba = a; best = d7; }
                    float out0 = xc0 + best;

                    d0 = a1L.x - xc1; d1 = a1R.x - xc1;
                    d2 = a1L.y - xc1; d3 = a1R.y - xc1;
                    d4 = f1.x - xc1;  d5 = f1.y - xc1;
                    d6 = a1Lz - xc1;  d7 = a1Rz - xc1;
                    best = d0; ba = fabsf(d0);
                    a = fabsf(d1); if (a < ba) { ba = a; best = d1; }
                    a = fabsf(d2); if (a < ba) { ba = a; best = d2; }
                    a = fabsf(d3); if (a < ba) { ba = a; best = d3; }
                    a = fabsf(d4); if (a < ba) { ba = a; best = d4; }
                    a = fabsf(d5); if (a < ba) { ba = a; best = d5; }
                    a = fabsf(d6); if (a < ba) { ba = a; best = d6; }
                    a = fabsf(d7); if (a < ba) { ba = a; best = d7; }
                    float out1 = xc1 + best;

                    *(float2*)(dp + (long)m * PITCH + oc0) = make_float2(out0, out1);
                }
            }
        }
    }
}

extern "C" void kernel_launch(void* const* d_in, const int* in_sizes, int n_in,
                              void* d_out, int out_size, void* d_ws, size_t ws_size,
                              hipStream_t stream) {
    (void)in_sizes; (void)n_in; (void)out_size; (void)ws_size;
    const float* img = (const float*)d_in[0];
    float* out = (float*)d_out;
    float* A = (float*)d_ws;
    float* B = A + 3L * PLANE;

    {
        int total = PW * PH;
        int g = (total + 255) / 256;
        sw_pad<<<dim3(g), dim3(256), 0, stream>>>(img, A);
    }
    dim3 grid(GX, GY, 3), block(BLK);
    for (int i = 0; i < 10; ++i) {
        const float* s = (i & 1) ? B : A;
        float* d = (i & 1) ? A : B;
        sw_iter<<<grid, block, 0, stream>>>(s, d);
    }
    // iter 9 (odd) writes A: final state in A.
    {
        int total = HH * WW;
        int g = (total + 255) / 256;
        sw_crop<<<dim3(g), dim3(256), 0, stream>>>(A, out);
    }
}

// Round 5
// 838.650 us; speedup vs baseline: 1.3825x; 1.0931x over previous
//
#include <hip/hip_runtime.h>
#include <math.h>

#pragma clang fp contract(off)

typedef float v2f __attribute__((ext_vector_type(2)));

#define RR 7
#define HH 2048
#define WW 2048
#define PH 2062
#define PW 2062
#define PITCH 2080
#define PLANE (PITCH * PH)

#define BLK 256
#define WOUT 496        // output cols per block (threads 0..247, 2 cols each)
#define TYB 32          // output rows per block (R3: 16 regressed; keep 32)
#define GX 5            // 5*496 = 2480 >= 2062
#define GY 65           // 65*32 = 2080 >= 2062
#define NCHUNK (TYB / 4)   // 8 chunks of 4 rows

__global__ __launch_bounds__(256) void sw_pad(const float* __restrict__ img,
                                              float* __restrict__ dst) {
    int idx = blockIdx.x * blockDim.x + threadIdx.x;
    if (idx >= PW * PH) return;
    int y = idx / PW, x = idx - y * PW;
    int sy = y - RR; sy = sy < 0 ? 0 : (sy > HH - 1 ? HH - 1 : sy);
    int sx = x - RR; sx = sx < 0 ? 0 : (sx > WW - 1 ? WW - 1 : sx);
    const float* p = img + ((long)sy * WW + sx) * 3;
    long o = (long)y * PITCH + x;
    dst[o] = p[0];
    dst[(long)PLANE + o] = p[1];
    dst[2L * PLANE + o] = p[2];
}

__global__ __launch_bounds__(256) void sw_crop(const float* __restrict__ src,
                                               float* __restrict__ out) {
    int idx = blockIdx.x * blockDim.x + threadIdx.x;
    if (idx >= HH * WW) return;
    int y = idx / WW, x = idx - y * WW;
    long o = (long)(y + RR) * PITCH + (x + RR);
    out[(long)idx * 3 + 0] = src[o];
    out[(long)idx * 3 + 1] = src[(long)PLANE + o];
    out[(long)idx * 3 + 2] = src[2L * PLANE + o];
}

// Streaming tap update for one pixel, packed (x,y) channels. i = tap 0..14.
// Chain order/rounding identical to verified R4 kernel (bit-exact requirement:
// the argmin selector flips on ulp changes and 10 iters amplify past tolerance).
#define PX_TAP(q, qxy, i, aL, aLz, aR, aRz, f, xc)                                      \
    do {                                                                                \
        if ((i) == 0) {                                                                 \
            aL = 0.125f * (qxy); aLz = 0.125f * (q).z;                                  \
            f = c15 * (qxy);                                                            \
        } else {                                                                        \
            if ((i) <= 7) {                                                             \
                aL = aL + 0.125f * (qxy); aLz = aLz + 0.125f * (q).z;                   \
            }                                                                           \
            if ((i) == 7) {                                                             \
                aR = 0.125f * (qxy); aRz = 0.125f * (q).z;                              \
                xc = (q).w;                                                             \
            }                                                                           \
            if ((i) > 7 && (i) <= 14) {                                                 \
                aR = aR + 0.125f * (qxy); aRz = aRz + 0.125f * (q).z;                   \
            }                                                                           \
            if ((i) <= 14) { f = f + c15 * (qxy); }                                     \
        }                                                                               \
    } while (0)

__global__ __launch_bounds__(BLK) void sw_iter(const float* __restrict__ src,
                                               float* __restrict__ dst) {
    // [chunk-row 0..3][half 0..1][col-idx 0..255], float4 {o1L,o1R,o1F,x}: 32 KB
    __shared__ float4 lds4[4 * 512];
    const int tid = threadIdx.x;
    const int x0 = blockIdx.x * WOUT;
    const int y0 = blockIdx.y * TYB;
    const int z = blockIdx.z;
    const float* sp = src + (long)z * PLANE;
    float* dp = dst + (long)z * PLANE;

    const int gc0 = x0 - 8 + 2 * tid;
    const bool gok = (gc0 >= 0) && (gc0 < PW);
    const int oc0 = x0 + 2 * tid;
    const bool comp = (tid < WOUT / 2) && (oc0 < PW);

    const float c15 = 1.0f / 15.0f;

    // register ring: input rows (slot = row & 15), packed {even col, odd col}
    v2f xab[16];
#pragma unroll
    for (int i = 0; i < 16; ++i) { xab[i] = (v2f){0.0f, 0.0f}; }

    // warm-up: rows y0-7 .. y0+6
#pragma unroll
    for (int k = 0; k < 14; ++k) {
        const int r = y0 - 7 + k;
        v2f v = (v2f){0.0f, 0.0f};
        if (gok && r >= 0) v = *(const v2f*)(sp + (long)r * PITCH + gc0);
        xab[(k + 9) & 15] = v;
    }

    // prefetch chunk 0's input rows (y0+7 .. y0+10) into registers
    v2f pf[4];
#pragma unroll
    for (int s = 0; s < 4; ++s) {
        const int t = y0 + 7 + s;
        v2f v = (v2f){0.0f, 0.0f};
        if (gok && t < PH) v = *(const v2f*)(sp + (long)t * PITCH + gc0);
        pf[s] = v;
    }

#pragma unroll
    for (int c = 0; c < NCHUNK; ++c) {
        __syncthreads();   // #1: horizontal pass done with LDS; prefetch loads
                           // have had the whole previous horizontal phase to land
        // ---- vertical stage: rows m = y0+4c+s, inputs from pf[] ----
#pragma unroll
        for (int s = 0; s < 4; ++s) {
            const int jm = (4 * c + s) & 15;
            xab[(jm + 7) & 15] = pf[s];

            v2f aL = 0.125f * xab[(jm + 9) & 15];
#pragma unroll
            for (int k = 1; k < 8; ++k) {
                aL = aL + 0.125f * xab[(jm + 9 + k) & 15];
            }
            v2f aR = 0.125f * xab[jm & 15];       // tap k=7 = row m
#pragma unroll
            for (int k = 8; k < 15; ++k) {
                aR = aR + 0.125f * xab[(jm + 9 + k) & 15];
            }
            v2f aF = c15 * xab[(jm + 9) & 15];
#pragma unroll
            for (int k = 1; k < 15; ++k) {
                aF = aF + c15 * xab[(jm + 9 + k) & 15];
            }
            const v2f X = xab[jm & 15];
            lds4[s * 512 + tid]       = make_float4(aL.x, aR.x, aF.x, X.x);
            lds4[s * 512 + 256 + tid] = make_float4(aL.y, aR.y, aF.y, X.y);
        }
        __syncthreads();   // #2: LDS rows ready (drain here is cheap: only just-
                           // issued ds_writes; no global loads outstanding)

        // ---- prefetch next chunk's rows NOW: the ~250-instr horizontal phase
        //      hides the load latency; next barrier's vmcnt(0) drain is ~free ----
        if (c + 1 < NCHUNK) {
#pragma unroll
            for (int s = 0; s < 4; ++s) {
                const int t = y0 + 4 * (c + 1) + 7 + s;
                v2f v = (v2f){0.0f, 0.0f};
                if (gok && t < PH) v = *(const v2f*)(sp + (long)t * PITCH + gc0);
                pf[s] = v;
            }
        }

        // ---- horizontal stage ----
        if (comp) {
#pragma unroll 1
            for (int s = 0; s < 4; ++s) {
                const int m = y0 + 4 * c + s;
                if (m >= PH) break;
                const float4* rowb = lds4 + s * 512;
                const float4* Eb = rowb + tid + 1;        // even cols 2t+2+2k
                const float4* Ob = rowb + 256 + tid;      // odd cols 2t+1+2k

                v2f a0L, a0R, f0; float a0Lz, a0Rz, xc0;
                v2f a1L, a1R, f1; float a1Lz, a1Rz, xc1;
#pragma unroll
                for (int j = 0; j < 16; ++j) {
                    float4 q = (j & 1) ? Eb[(j - 1) >> 1] : Ob[j >> 1];
                    v2f qxy = (v2f){q.x, q.y};
                    if (j <= 14) PX_TAP(q, qxy, j, a0L, a0Lz, a0R, a0Rz, f0, xc0);
                    if (j >= 1)  PX_TAP(q, qxy, (j - 1), a1L, a1Lz, a1R, a1Rz, f1, xc1);
                }

                // argmin: scalar, candidate order identical to baseline
                float d0 = a0L.x - xc0, d1 = a0R.x - xc0;
                float d2 = a0L.y - xc0, d3 = a0R.y - xc0;
                float d4 = f0.x - xc0,  d5 = f0.y - xc0;
                float d6 = a0Lz - xc0,  d7 = a0Rz - xc0;
                float best = d0, ba = fabsf(d0), a;
                a = fabsf(d1); if (a < ba) { ba = a; best = d1; }
                a = fabsf(d2); if (a < ba) { ba = a; best = d2; }
                a = fabsf(d3); if (a < ba) { ba = a; best = d3; }
                a = fabsf(d4); if (a < ba) { ba = a; best = d4; }
                a = fabsf(d5); if (a < ba) { ba = a; best = d5; }
                a = fabsf(d6); if (a < ba) { ba = a; best = d6; }
                a = fabsf(d7); if (a < ba) { ba = a; best = d7; }
                float out0 = xc0 + best;

                d0 = a1L.x - xc1; d1 = a1R.x - xc1;
                d2 = a1L.y - xc1; d3 = a1R.y - xc1;
                d4 = f1.x - xc1;  d5 = f1.y - xc1;
                d6 = a1Lz - xc1;  d7 = a1Rz - xc1;
                best = d0; ba = fabsf(d0);
                a = fabsf(d1); if (a < ba) { ba = a; best = d1; }
                a = fabsf(d2); if (a < ba) { ba = a; best = d2; }
                a = fabsf(d3); if (a < ba) { ba = a; best = d3; }
                a = fabsf(d4); if (a < ba) { ba = a; best = d4; }
                a = fabsf(d5); if (a < ba) { ba = a; best = d5; }
                a = fabsf(d6); if (a < ba) { ba = a; best = d6; }
                a = fabsf(d7); if (a < ba) { ba = a; best = d7; }
                float out1 = xc1 + best;

                *(float2*)(dp + (long)m * PITCH + oc0) = make_float2(out0, out1);
            }
        }
    }
}

extern "C" void kernel_launch(void* const* d_in, const int* in_sizes, int n_in,
                              void* d_out, int out_size, void* d_ws, size_t ws_size,
                              hipStream_t stream) {
    (void)in_sizes; (void)n_in; (void)out_size; (void)ws_size;
    const float* img = (const float*)d_in[0];
    float* out = (float*)d_out;
    float* A = (float*)d_ws;
    float* B = A + 3L * PLANE;

    {
        int total = PW * PH;
        int g = (total + 255) / 256;
        sw_pad<<<dim3(g), dim3(256), 0, stream>>>(img, A);
    }
    dim3 grid(GX, GY, 3), block(BLK);
    for (int i = 0; i < 10; ++i) {
        const float* s = (i & 1) ? B : A;
        float* d = (i & 1) ? A : B;
        sw_iter<<<grid, block, 0, stream>>>(s, d);
    }
    // iter 9 (odd) writes A: final state in A.
    {
        int total = HH * WW;
        int g = (total + 255) / 256;
        sw_crop<<<dim3(g), dim3(256), 0, stream>>>(A, out);
    }
}